// Round 1
// baseline (929.290 us; speedup 1.0000x reference)
//
#include <hip/hip_runtime.h>
#include <cstdint>

#define C_LEN 4096
#define E_DIM 1024
#define NBATCH 4

typedef __attribute__((ext_vector_type(4))) float f32x4;
typedef __attribute__((ext_vector_type(8))) short bf16x8;
typedef __attribute__((ext_vector_type(4))) unsigned short u16x4;

__device__ __forceinline__ unsigned short f2bf(float f) {
  uint32_t u = __builtin_bit_cast(uint32_t, f);
  return (unsigned short)((u + 0x7fffu + ((u >> 16) & 1u)) >> 16);
}

__device__ __forceinline__ void gl_lds16(const void* g, void* l) {
  __builtin_amdgcn_global_load_lds(
      (const __attribute__((address_space(1))) void*)g,
      (__attribute__((address_space(3))) void*)l, 16, 0, 0);
}

// -------- RoPE cos/sin table: [C][E/2] f32 each, computed in double --------
__global__ __launch_bounds__(256) void rope_table(float* __restrict__ cosT,
                                                  float* __restrict__ sinT) {
  int idx = blockIdx.x * 256 + threadIdx.x;  // over C*E/2 = 2,097,152
  int pos = idx >> 9;
  int i = idx & 511;
  // inv_freq = 10000^(-2i/1024)
  double inv = exp(((double)(-2 * i) / 1024.0) * 9.210340371976184);
  double a = (double)pos * inv;
  cosT[idx] = (float)cos(a);
  sinT[idx] = (float)sin(a);
}

// -------- f32 -> bf16 convert (4 elems/thread) --------
__global__ __launch_bounds__(256) void cvt_bf16_k(const float* __restrict__ in,
                                                  unsigned short* __restrict__ out,
                                                  int n4) {
  int i = blockIdx.x * 256 + threadIdx.x;
  if (i < n4) {
    f32x4 v = *(const f32x4*)(in + (long)i * 4);
    u16x4 o = {f2bf(v.x), f2bf(v.y), f2bf(v.z), f2bf(v.w)};
    *(u16x4*)(out + (long)i * 4) = o;
  }
}

// -------- BT GEMM: A[M][K] bf16 row-major, B[N][K] bf16 row-major (B^T form) --------
// 128x128 tile, BK=32, 256 threads = 4 waves (2x2), each wave 64x64 (4x4 frags).
// MODE 0: epilogue RoPE, write bf16 [M][N]           (Q/K projection)
// MODE 1: epilogue transpose, write bf16 V_t[b][e][c] (V projection)
// MODE 2: epilogue *1/32 + mask, write f32 scores     (QK^T)
template <int MODE>
__global__ __launch_bounds__(256) void gemm_bt(
    const unsigned short* __restrict__ A, const unsigned short* __restrict__ Bm,
    long batchA, long batchB, long batchOut, int M, int N, int K,
    unsigned short* __restrict__ outB, float* __restrict__ outF,
    const float* __restrict__ cosT, const float* __restrict__ sinT,
    const float* __restrict__ mask) {
  __shared__ unsigned short sA[128 * 32];
  __shared__ unsigned short sB[128 * 32];
  const int tid = threadIdx.x;
  const int lane = tid & 63;
  const int wid = tid >> 6;
  const int wm = wid >> 1, wn = wid & 1;
  const int bz = blockIdx.z;
  const unsigned short* Ag = A + batchA * bz + (long)(blockIdx.x * 128) * K;
  const unsigned short* Bg = Bm + batchB * bz + (long)(blockIdx.y * 128) * K;
  const int srow = tid >> 2;       // staging row within 64-row half
  const int scol = (tid & 3) * 8;  // staging col (elements)

  f32x4 acc[4][4];
#pragma unroll
  for (int m = 0; m < 4; ++m)
#pragma unroll
    for (int n = 0; n < 4; ++n) acc[m][n] = {0.f, 0.f, 0.f, 0.f};

  const int kgrp = lane >> 4;
  const int r16 = lane & 15;

  for (int k0 = 0; k0 < K; k0 += 32) {
#pragma unroll
    for (int i = 0; i < 2; ++i) {
      gl_lds16(Ag + (long)(i * 64 + srow) * K + k0 + scol, sA + i * 2048 + wid * 512);
      gl_lds16(Bg + (long)(i * 64 + srow) * K + k0 + scol, sB + i * 2048 + wid * 512);
    }
    __syncthreads();  // compiler drains vmcnt before barrier -> staged data visible
    bf16x8 af[4], bfr[4];
#pragma unroll
    for (int m = 0; m < 4; ++m)
      af[m] = *(const bf16x8*)&sA[(wm * 64 + m * 16 + r16) * 32 + kgrp * 8];
#pragma unroll
    for (int n = 0; n < 4; ++n)
      bfr[n] = *(const bf16x8*)&sB[(wn * 64 + n * 16 + r16) * 32 + kgrp * 8];
#pragma unroll
    for (int m = 0; m < 4; ++m)
#pragma unroll
      for (int n = 0; n < 4; ++n)
        acc[m][n] = __builtin_amdgcn_mfma_f32_16x16x32_bf16(af[m], bfr[n], acc[m][n], 0, 0, 0);
    __syncthreads();  // all waves done reading before next stage overwrites
  }

  const int row0 = blockIdx.x * 128 + wm * 64;
  const int col0 = blockIdx.y * 128 + wn * 64;
#pragma unroll
  for (int m = 0; m < 4; ++m) {
#pragma unroll
    for (int n = 0; n < 4; ++n) {
#pragma unroll
      for (int r = 0; r < 4; ++r) {
        float v = acc[m][n][r];
        int row = row0 + m * 16 + kgrp * 4 + r;  // C/D: col=lane&15, row=(lane>>4)*4+r
        int col = col0 + n * 16 + r16;
        if (MODE == 0) {
          // RoPE: pair partner lives in lane^1 (col^1), same row/reg.
          float p = __shfl_xor(v, 1);
          int pos = row & (C_LEN - 1);
          int i2 = col >> 1;
          float c = cosT[pos * (E_DIM / 2) + i2];
          float s = sinT[pos * (E_DIM / 2) + i2];
          float rv = v * c + ((col & 1) ? p * s : -p * s);
          outB[(long)row * N + col] = f2bf(rv);
        } else if (MODE == 1) {
          int b = row >> 12;  // C_LEN = 4096
          int cc = row & (C_LEN - 1);
          outB[(long)b * E_DIM * C_LEN + (long)col * C_LEN + cc] = f2bf(v);
        } else {
          float sc = v * 0.03125f + mask[(long)row * C_LEN + col];
          outF[batchOut * bz + (long)row * C_LEN + col] = sc;
        }
      }
    }
  }
}

// -------- PV GEMM: A = P f32 [C][C] (reg-staged, converted to bf16), B = V_t bf16 [E][C] --------
__global__ __launch_bounds__(256) void gemm_pv(const float* __restrict__ P,
                                               const unsigned short* __restrict__ Vt,
                                               float* __restrict__ out) {
  __shared__ unsigned short sA[128 * 32];
  __shared__ unsigned short sB[128 * 32];
  const int tid = threadIdx.x;
  const int lane = tid & 63;
  const int wid = tid >> 6;
  const int wm = wid >> 1, wn = wid & 1;
  const int bz = blockIdx.z;
  const float* Pg = P + (long)bz * C_LEN * C_LEN + (long)(blockIdx.x * 128) * C_LEN;
  const unsigned short* Bg = Vt + (long)bz * E_DIM * C_LEN + (long)(blockIdx.y * 128) * C_LEN;
  const int srow = tid >> 2;
  const int scol = (tid & 3) * 8;

  f32x4 acc[4][4];
#pragma unroll
  for (int m = 0; m < 4; ++m)
#pragma unroll
    for (int n = 0; n < 4; ++n) acc[m][n] = {0.f, 0.f, 0.f, 0.f};

  const int kgrp = lane >> 4;
  const int r16 = lane & 15;

  for (int k0 = 0; k0 < C_LEN; k0 += 32) {
    // A: load f32, convert to bf16, ds_write (1024 elems per pass, 4 passes)
#pragma unroll
    for (int j = 0; j < 4; ++j) {
      int e = j * 1024 + tid * 4;
      int row = e >> 5, cx = e & 31;
      f32x4 v = *(const f32x4*)(Pg + (long)row * C_LEN + k0 + cx);
      u16x4 o = {f2bf(v.x), f2bf(v.y), f2bf(v.z), f2bf(v.w)};
      *(u16x4*)&sA[row * 32 + cx] = o;
    }
#pragma unroll
    for (int i = 0; i < 2; ++i)
      gl_lds16(Bg + (long)(i * 64 + srow) * C_LEN + k0 + scol, sB + i * 2048 + wid * 512);
    __syncthreads();
    bf16x8 af[4], bfr[4];
#pragma unroll
    for (int m = 0; m < 4; ++m)
      af[m] = *(const bf16x8*)&sA[(wm * 64 + m * 16 + r16) * 32 + kgrp * 8];
#pragma unroll
    for (int n = 0; n < 4; ++n)
      bfr[n] = *(const bf16x8*)&sB[(wn * 64 + n * 16 + r16) * 32 + kgrp * 8];
#pragma unroll
    for (int m = 0; m < 4; ++m)
#pragma unroll
      for (int n = 0; n < 4; ++n)
        acc[m][n] = __builtin_amdgcn_mfma_f32_16x16x32_bf16(af[m], bfr[n], acc[m][n], 0, 0, 0);
    __syncthreads();
  }

  const int row0 = blockIdx.x * 128 + wm * 64;
  const int col0 = blockIdx.y * 128 + wn * 64;
#pragma unroll
  for (int m = 0; m < 4; ++m)
#pragma unroll
    for (int n = 0; n < 4; ++n)
#pragma unroll
      for (int r = 0; r < 4; ++r) {
        int row = row0 + m * 16 + kgrp * 4 + r;
        int col = col0 + n * 16 + r16;
        out[(long)bz * C_LEN * E_DIM + (long)row * E_DIM + col] = acc[m][n][r];
      }
}

// -------- row softmax in place: one block per row of 4096 f32 --------
__global__ __launch_bounds__(256) void softmax_rows(float* __restrict__ w) {
  long row = blockIdx.x;
  float* p = w + row * C_LEN;
  int t = threadIdx.x;
  int wid = t >> 6;
  f32x4 v[4];
  float mx = -3.4e38f;
#pragma unroll
  for (int j = 0; j < 4; ++j) {
    v[j] = *(const f32x4*)(p + j * 1024 + t * 4);
    mx = fmaxf(mx, fmaxf(fmaxf(v[j].x, v[j].y), fmaxf(v[j].z, v[j].w)));
  }
#pragma unroll
  for (int o = 1; o < 64; o <<= 1) mx = fmaxf(mx, __shfl_xor(mx, o));
  __shared__ float redm[4];
  if ((t & 63) == 0) redm[wid] = mx;
  __syncthreads();
  mx = fmaxf(fmaxf(redm[0], redm[1]), fmaxf(redm[2], redm[3]));
  float sum = 0.f;
#pragma unroll
  for (int j = 0; j < 4; ++j) {
    v[j].x = __expf(v[j].x - mx);
    v[j].y = __expf(v[j].y - mx);
    v[j].z = __expf(v[j].z - mx);
    v[j].w = __expf(v[j].w - mx);
    sum += v[j].x + v[j].y + v[j].z + v[j].w;
  }
#pragma unroll
  for (int o = 1; o < 64; o <<= 1) sum += __shfl_xor(sum, o);
  __shared__ float reds[4];
  if ((t & 63) == 0) reds[wid] = sum;
  __syncthreads();
  sum = reds[0] + reds[1] + reds[2] + reds[3];
  float inv = 1.0f / sum;
#pragma unroll
  for (int j = 0; j < 4; ++j) {
    v[j].x *= inv;
    v[j].y *= inv;
    v[j].z *= inv;
    v[j].w *= inv;
    *(f32x4*)(p + j * 1024 + t * 4) = v[j];
  }
}

extern "C" void kernel_launch(void* const* d_in, const int* in_sizes, int n_in,
                              void* d_out, int out_size, void* d_ws, size_t ws_size,
                              hipStream_t stream) {
  const float* x = (const float*)d_in[0];
  const float* mask = (const float*)d_in[1];
  const float* Wq = (const float*)d_in[2];
  const float* Wk = (const float*)d_in[3];
  const float* Wv = (const float*)d_in[4];
  float* out = (float*)d_out;                              // [B][C][E]
  float* weights = out + (long)NBATCH * C_LEN * E_DIM;     // [B][C][C]

  char* ws = (char*)d_ws;
  float* cosT = (float*)(ws);                              // 8 MB
  float* sinT = (float*)(ws + (8l << 20));                 // 8 MB
  unsigned short* x_bf = (unsigned short*)(ws + (16l << 20));   // 32 MB
  unsigned short* Wq_bf = (unsigned short*)(ws + (48l << 20));  // 2 MB
  unsigned short* Wk_bf = (unsigned short*)(ws + (50l << 20));  // 2 MB
  unsigned short* Wv_bf = (unsigned short*)(ws + (52l << 20));  // 2 MB
  unsigned short* Q_bf = (unsigned short*)(ws + (54l << 20));   // 32 MB
  unsigned short* K_bf = (unsigned short*)(ws + (86l << 20));   // 32 MB
  unsigned short* Vt = (unsigned short*)(ws + (118l << 20));    // 32 MB  (total 150 MB)

  dim3 blk(256);

  rope_table<<<dim3((C_LEN * (E_DIM / 2)) / 256), blk, 0, stream>>>(cosT, sinT);
  cvt_bf16_k<<<dim3(16384), blk, 0, stream>>>(x, x_bf, 4194304);
  cvt_bf16_k<<<dim3(1024), blk, 0, stream>>>(Wq, Wq_bf, 262144);
  cvt_bf16_k<<<dim3(1024), blk, 0, stream>>>(Wk, Wk_bf, 262144);
  cvt_bf16_k<<<dim3(1024), blk, 0, stream>>>(Wv, Wv_bf, 262144);

  // Q, K projections with fused RoPE; V with transposed store
  gemm_bt<0><<<dim3(128, 8, 1), blk, 0, stream>>>(x_bf, Wq_bf, 0, 0, 0, 16384, 1024, 1024,
                                                  Q_bf, nullptr, cosT, sinT, nullptr);
  gemm_bt<0><<<dim3(128, 8, 1), blk, 0, stream>>>(x_bf, Wk_bf, 0, 0, 0, 16384, 1024, 1024,
                                                  K_bf, nullptr, cosT, sinT, nullptr);
  gemm_bt<1><<<dim3(128, 8, 1), blk, 0, stream>>>(x_bf, Wv_bf, 0, 0, 0, 16384, 1024, 1024,
                                                  Vt, nullptr, nullptr, nullptr, nullptr);

  // scores = QK^T/32 + mask  -> weights region (f32)
  gemm_bt<2><<<dim3(32, 32, 4), blk, 0, stream>>>(
      Q_bf, K_bf, (long)C_LEN * E_DIM, (long)C_LEN * E_DIM, (long)C_LEN * C_LEN,
      4096, 4096, 1024, nullptr, weights, nullptr, nullptr, mask);

  softmax_rows<<<dim3(NBATCH * C_LEN), blk, 0, stream>>>(weights);

  // out = weights @ V   (A f32 reg-staged -> bf16, B = V_t)
  gemm_pv<<<dim3(32, 8, 4), blk, 0, stream>>>(weights, Vt, out);
}